// Round 1
// baseline (856.206 us; speedup 1.0000x reference)
//
#include <hip/hip_runtime.h>

#define CIN 61
constexpr float EPS = 1e-5f;
constexpr double SCALE = 16777216.0;  // 2^24 fixed-point for deterministic stat sums

// ---- ws layout ----
// [0,4096):          long long stats[512]  (sum1,sq1,sum2,sq2,sumS,sqS,sumA,sqA per 64ch)
// [4096,6144):       float coef[512]       (a1,c1,a2,c2,aS,cS,aF,cF per 64ch)
// [8192, +N*256):    agg  (u32 encoded max, then f32 in place)
// [.., +N*256):      s    (shortcut pre-BN, f32)

__global__ __launch_bounds__(256) void k_init(unsigned int* w, int total) {
  int i = blockIdx.x * 256 + threadIdx.x;
  if (i < total) w[i] = 0u;
}

__device__ __forceinline__ void stat_reduce(float val, float* red, long long* dst_ll) {
  int tid = threadIdx.x;
  red[tid] = val;
  __syncthreads();
  if (tid < 64) {
    float t = red[tid] + red[tid + 64] + red[tid + 128] + red[tid + 192];
    atomicAdd((unsigned long long*)&dst_ll[tid],
              (unsigned long long)(long long)((double)t * SCALE));
  }
  __syncthreads();
}

// pass 1: t1 = relu(msg@W1+b1), accumulate per-channel stats of t1 over E
__global__ __launch_bounds__(256) void k_edge1(
    const float* __restrict__ x, const float* __restrict__ pos,
    const int* __restrict__ ei, const float* __restrict__ W1,
    const float* __restrict__ b1, long long* __restrict__ stats, int E) {
  const int tid = threadIdx.x, lane = tid & 63, wv = tid >> 6;
  float w1c[64];
#pragma unroll
  for (int k = 0; k < 64; ++k) w1c[k] = W1[k * 64 + lane];
  const float b1v = b1[lane];
  __shared__ float lmsg[4][64];
  __shared__ float red[256];
  float ssum = 0.f, ssq = 0.f;
  const int nq = E >> 2;
  for (int q = blockIdx.x; q < nq; q += gridDim.x) {
    const int e = (q << 2) + wv;
    const int src = ei[e];
    float m;
    if (lane < CIN) {
      m = x[src * CIN + lane];
    } else {
      const int dst = ei[E + e];
      const int d = lane - CIN;
      m = pos[src * 3 + d] - pos[dst * 3 + d];
    }
    lmsg[wv][lane] = m;
    __syncthreads();
    float acc = b1v;
    const float4* mr = (const float4*)&lmsg[wv][0];
#pragma unroll
    for (int k4 = 0; k4 < 16; ++k4) {
      float4 v = mr[k4];
      acc = fmaf(v.x, w1c[4 * k4 + 0], acc);
      acc = fmaf(v.y, w1c[4 * k4 + 1], acc);
      acc = fmaf(v.z, w1c[4 * k4 + 2], acc);
      acc = fmaf(v.w, w1c[4 * k4 + 3], acc);
    }
    float t1 = fmaxf(acc, 0.f);
    ssum += t1;
    ssq = fmaf(t1, t1, ssq);
    __syncthreads();
  }
  stat_reduce(ssum, red, stats + 0);
  stat_reduce(ssq, red, stats + 64);
}

// pass 2: recompute t1, h1 = a1*t1+c1 (folded BN1), t2 = relu(h1@W2+b2),
// stats of t2, scatter-max encoded t2 into agg
__global__ __launch_bounds__(256) void k_edge2(
    const float* __restrict__ x, const float* __restrict__ pos,
    const int* __restrict__ ei, const float* __restrict__ W1,
    const float* __restrict__ b1, const float* __restrict__ W2,
    const float* __restrict__ b2, const float* __restrict__ coef,
    long long* __restrict__ stats, unsigned int* __restrict__ agg, int E) {
  const int tid = threadIdx.x, lane = tid & 63, wv = tid >> 6;
  float w1c[64], w2c[64];
#pragma unroll
  for (int k = 0; k < 64; ++k) w1c[k] = W1[k * 64 + lane];
#pragma unroll
  for (int k = 0; k < 64; ++k) w2c[k] = W2[k * 64 + lane];
  const float b1v = b1[lane], b2v = b2[lane];
  const float a1v = coef[lane], c1v = coef[64 + lane];
  __shared__ float lmsg[4][64];
  __shared__ float lh[4][64];
  __shared__ float red[256];
  float ssum = 0.f, ssq = 0.f;
  const int nq = E >> 2;
  for (int q = blockIdx.x; q < nq; q += gridDim.x) {
    const int e = (q << 2) + wv;
    const int src = ei[e];
    const int dst = ei[E + e];
    float m;
    if (lane < CIN) {
      m = x[src * CIN + lane];
    } else {
      const int d = lane - CIN;
      m = pos[src * 3 + d] - pos[dst * 3 + d];
    }
    lmsg[wv][lane] = m;
    __syncthreads();
    float acc = b1v;
    const float4* mr = (const float4*)&lmsg[wv][0];
#pragma unroll
    for (int k4 = 0; k4 < 16; ++k4) {
      float4 v = mr[k4];
      acc = fmaf(v.x, w1c[4 * k4 + 0], acc);
      acc = fmaf(v.y, w1c[4 * k4 + 1], acc);
      acc = fmaf(v.z, w1c[4 * k4 + 2], acc);
      acc = fmaf(v.w, w1c[4 * k4 + 3], acc);
    }
    float h1 = fmaf(a1v, fmaxf(acc, 0.f), c1v);
    lh[wv][lane] = h1;
    __syncthreads();
    float acc2 = b2v;
    const float4* hr = (const float4*)&lh[wv][0];
#pragma unroll
    for (int k4 = 0; k4 < 16; ++k4) {
      float4 v = hr[k4];
      acc2 = fmaf(v.x, w2c[4 * k4 + 0], acc2);
      acc2 = fmaf(v.y, w2c[4 * k4 + 1], acc2);
      acc2 = fmaf(v.z, w2c[4 * k4 + 2], acc2);
      acc2 = fmaf(v.w, w2c[4 * k4 + 3], acc2);
    }
    float t2 = fmaxf(acc2, 0.f);
    ssum += t2;
    ssq = fmaf(t2, t2, ssq);
    // t2 >= 0: bits are order-preserving; |0x80000000 distinguishes "touched" from empty(0)
    atomicMax(&agg[(unsigned)dst * 64u + (unsigned)lane],
              __float_as_uint(t2) | 0x80000000u);
    __syncthreads();
  }
  stat_reduce(ssum, red, stats + 128);
  stat_reduce(ssq, red, stats + 192);
}

// shortcut: s = x@Ws + bs (no relu), store + stats over N
__global__ __launch_bounds__(256) void k_nodes(
    const float* __restrict__ x, const float* __restrict__ Ws,
    const float* __restrict__ bs, float* __restrict__ s_out,
    long long* __restrict__ stats, int N) {
  const int tid = threadIdx.x, lane = tid & 63, wv = tid >> 6;
  float wc[64];
#pragma unroll
  for (int k = 0; k < 64; ++k) wc[k] = (k < CIN) ? Ws[k * 64 + lane] : 0.f;
  const float bsv = bs[lane];
  __shared__ float lrow[4][64];
  __shared__ float red[256];
  float ssum = 0.f, ssq = 0.f;
  const int nq = N >> 2;
  for (int q = blockIdx.x; q < nq; q += gridDim.x) {
    const int n = (q << 2) + wv;
    lrow[wv][lane] = (lane < CIN) ? x[n * CIN + lane] : 0.f;
    __syncthreads();
    float acc = bsv;
    const float4* rr = (const float4*)&lrow[wv][0];
#pragma unroll
    for (int k4 = 0; k4 < 16; ++k4) {
      float4 v = rr[k4];
      acc = fmaf(v.x, wc[4 * k4 + 0], acc);
      acc = fmaf(v.y, wc[4 * k4 + 1], acc);
      acc = fmaf(v.z, wc[4 * k4 + 2], acc);
      acc = fmaf(v.w, wc[4 * k4 + 3], acc);
    }
    s_out[n * 64 + lane] = acc;
    ssum += acc;
    ssq = fmaf(acc, acc, ssq);
    __syncthreads();
  }
  stat_reduce(ssum, red, stats + 256);
  stat_reduce(ssq, red, stats + 320);
}

// generic BN-coefficient finalize: a = g*rsqrt(var+eps), c = be - mean*a
__global__ void k_coef(const long long* __restrict__ sum,
                       const long long* __restrict__ sq,
                       const float* __restrict__ g, const float* __restrict__ be,
                       float* __restrict__ a_out, float* __restrict__ c_out,
                       double inv) {
  int c = threadIdx.x;
  double m = (double)sum[c] * inv;
  double v = (double)sq[c] * inv - m * m;
  float rs = rsqrtf((float)v + EPS);
  float a = g[c] * rs;
  a_out[c] = a;
  c_out[c] = fmaf(-(float)m, a, be[c]);
}

// decode scatter-max, apply BN2 affine (a2>0), replace empty with 0, stats over N
__global__ __launch_bounds__(256) void k_aggfix(
    unsigned int* __restrict__ agg, const float* __restrict__ coef,
    long long* __restrict__ stats, int total) {
  const int tid = threadIdx.x;
  const int c = tid & 63;
  const float a2 = coef[128 + c], c2 = coef[192 + c];
  __shared__ float red[256];
  float ssum = 0.f, ssq = 0.f;
  const int step = gridDim.x * 256;
  for (int i = blockIdx.x * 256 + tid; i < total; i += step) {
    unsigned int u = agg[i];
    float v = (u == 0u) ? 0.f : fmaf(a2, __uint_as_float(u & 0x7fffffffu), c2);
    ((float*)agg)[i] = v;
    ssum += v;
    ssq = fmaf(v, v, ssq);
  }
  stat_reduce(ssum, red, stats + 384);
  stat_reduce(ssq, red, stats + 448);
}

__global__ __launch_bounds__(256) void k_final(
    const float* __restrict__ aggf, const float* __restrict__ s,
    const float* __restrict__ coef, float* __restrict__ out, int total) {
  int i = blockIdx.x * 256 + threadIdx.x;
  if (i >= total) return;
  int c = i & 63;
  float v = fmaf(coef[384 + c], aggf[i], coef[448 + c]) +
            fmaf(coef[256 + c], s[i], coef[320 + c]);
  out[i] = fmaxf(v, 0.f);
}

extern "C" void kernel_launch(void* const* d_in, const int* in_sizes, int n_in,
                              void* d_out, int out_size, void* d_ws, size_t ws_size,
                              hipStream_t stream) {
  const float* x   = (const float*)d_in[0];
  const float* pos = (const float*)d_in[1];
  const int*   ei  = (const int*)d_in[2];
  const float* W1  = (const float*)d_in[3];
  const float* b1  = (const float*)d_in[4];
  const float* g1  = (const float*)d_in[5];
  const float* be1 = (const float*)d_in[6];
  const float* W2  = (const float*)d_in[7];
  const float* b2  = (const float*)d_in[8];
  const float* g2  = (const float*)d_in[9];
  const float* be2 = (const float*)d_in[10];
  const float* Ws  = (const float*)d_in[11];
  const float* bs  = (const float*)d_in[12];
  const float* gs  = (const float*)d_in[13];
  const float* bes = (const float*)d_in[14];
  const float* gf  = (const float*)d_in[15];
  const float* bef = (const float*)d_in[16];
  const int N = in_sizes[0] / CIN;   // 50000
  const int E = in_sizes[2] / 2;     // 800000

  char* ws = (char*)d_ws;
  long long* stats  = (long long*)ws;
  float* coef       = (float*)(ws + 4096);
  unsigned int* agg = (unsigned int*)(ws + 8192);
  float* sbuf       = (float*)(ws + 8192 + (size_t)N * 256);

  const double invE = 1.0 / (SCALE * (double)E);
  const double invN = 1.0 / (SCALE * (double)N);
  const int total = N * 64;
  const int initWords = 2048 + total;

  hipLaunchKernelGGL(k_init, dim3((initWords + 255) / 256), dim3(256), 0, stream,
                     (unsigned int*)ws, initWords);
  hipLaunchKernelGGL(k_edge1, dim3(2048), dim3(256), 0, stream,
                     x, pos, ei, W1, b1, stats, E);
  hipLaunchKernelGGL(k_coef, dim3(1), dim3(64), 0, stream,
                     stats + 0, stats + 64, g1, be1, coef + 0, coef + 64, invE);
  hipLaunchKernelGGL(k_edge2, dim3(2048), dim3(256), 0, stream,
                     x, pos, ei, W1, b1, W2, b2, coef, stats, agg, E);
  hipLaunchKernelGGL(k_nodes, dim3(1024), dim3(256), 0, stream,
                     x, Ws, bs, sbuf, stats, N);
  hipLaunchKernelGGL(k_coef, dim3(1), dim3(64), 0, stream,
                     stats + 128, stats + 192, g2, be2, coef + 128, coef + 192, invE);
  hipLaunchKernelGGL(k_coef, dim3(1), dim3(64), 0, stream,
                     stats + 256, stats + 320, gs, bes, coef + 256, coef + 320, invN);
  hipLaunchKernelGGL(k_aggfix, dim3(2048), dim3(256), 0, stream,
                     agg, coef, stats, total);
  hipLaunchKernelGGL(k_coef, dim3(1), dim3(64), 0, stream,
                     stats + 384, stats + 448, gf, bef, coef + 384, coef + 448, invN);
  hipLaunchKernelGGL(k_final, dim3((total + 255) / 256), dim3(256), 0, stream,
                     (const float*)agg, sbuf, coef, (float*)d_out, total);
}

// Round 2
// 439.741 us; speedup vs baseline: 1.9471x; 1.9471x over previous
//
#include <hip/hip_runtime.h>

#define CIN 61
constexpr float EPS = 1e-5f;
constexpr double SCALE = 16777216.0;  // 2^24 fixed-point deterministic stat sums

using s16x8 = __attribute__((ext_vector_type(8))) short;
using fx4   = __attribute__((ext_vector_type(4))) float;

static __device__ __forceinline__ unsigned short f2bf(float f) {
  unsigned int u = __float_as_uint(f);
  u = (u + 0x7fffu + ((u >> 16) & 1u)) >> 16;
  return (unsigned short)u;
}
static __device__ __forceinline__ float bf2f(unsigned short h) {
  return __uint_as_float(((unsigned int)h) << 16);
}

__device__ __forceinline__ void stat_reduce(float val, float* red, long long* dst_ll) {
  int tid = threadIdx.x;
  red[tid] = val;
  __syncthreads();
  if (tid < 64) {
    float t = red[tid] + red[tid + 64] + red[tid + 128] + red[tid + 192];
    atomicAdd((unsigned long long*)&dst_ll[tid],
              (unsigned long long)(long long)((double)t * SCALE));
  }
  __syncthreads();
}

// ---- node GEMV: y = bf16(x @ W1[:61] + b1) ----
__global__ __launch_bounds__(256) void k_y(
    const float* __restrict__ x, const float* __restrict__ W1,
    const float* __restrict__ b1, unsigned short* __restrict__ y, int N) {
  const int tid = threadIdx.x, lane = tid & 63, wv = tid >> 6;
  float w[64];
#pragma unroll
  for (int k = 0; k < 64; ++k) w[k] = (k < CIN) ? W1[k * 64 + lane] : 0.f;
  const float bv = b1[lane];
  __shared__ float lrow[4][64];
  const int nq = N >> 2;
  for (int q = blockIdx.x; q < nq; q += gridDim.x) {
    const int n = (q << 2) + wv;
    lrow[wv][lane] = (lane < CIN) ? x[n * CIN + lane] : 0.f;
    __syncthreads();
    float a0 = bv, a1 = 0.f, a2 = 0.f, a3 = 0.f;
    const float4* rr = (const float4*)&lrow[wv][0];
#pragma unroll
    for (int k4 = 0; k4 < 16; ++k4) {
      float4 v = rr[k4];
      a0 = fmaf(v.x, w[4 * k4 + 0], a0);
      a1 = fmaf(v.y, w[4 * k4 + 1], a1);
      a2 = fmaf(v.z, w[4 * k4 + 2], a2);
      a3 = fmaf(v.w, w[4 * k4 + 3], a3);
    }
    y[(size_t)n * 64 + lane] = f2bf((a0 + a1) + (a2 + a3));
    __syncthreads();
  }
}

// ---- shortcut GEMV: s = x @ Ws + bs (f32) + stats over N ----
__global__ __launch_bounds__(256) void k_short(
    const float* __restrict__ x, const float* __restrict__ Ws,
    const float* __restrict__ bs, float* __restrict__ s_out,
    long long* __restrict__ stats, int N) {
  const int tid = threadIdx.x, lane = tid & 63, wv = tid >> 6;
  float w[64];
#pragma unroll
  for (int k = 0; k < 64; ++k) w[k] = (k < CIN) ? Ws[k * 64 + lane] : 0.f;
  const float bv = bs[lane];
  __shared__ float lrow[4][64];
  __shared__ float red[256];
  float ssum = 0.f, ssq = 0.f;
  const int nq = N >> 2;
  for (int q = blockIdx.x; q < nq; q += gridDim.x) {
    const int n = (q << 2) + wv;
    lrow[wv][lane] = (lane < CIN) ? x[n * CIN + lane] : 0.f;
    __syncthreads();
    float a0 = bv, a1 = 0.f, a2 = 0.f, a3 = 0.f;
    const float4* rr = (const float4*)&lrow[wv][0];
#pragma unroll
    for (int k4 = 0; k4 < 16; ++k4) {
      float4 v = rr[k4];
      a0 = fmaf(v.x, w[4 * k4 + 0], a0);
      a1 = fmaf(v.y, w[4 * k4 + 1], a1);
      a2 = fmaf(v.z, w[4 * k4 + 2], a2);
      a3 = fmaf(v.w, w[4 * k4 + 3], a3);
    }
    const float acc = (a0 + a1) + (a2 + a3);
    s_out[(size_t)n * 64 + lane] = acc;
    ssum += acc;
    ssq = fmaf(acc, acc, ssq);
    __syncthreads();
  }
  stat_reduce(ssum, red, stats + 256);
  stat_reduce(ssq, red, stats + 320);
}

// ---- edge pass 1: t1 = relu(y[src] + (pos_src-pos_dst)@Wp), store bf16, stats ----
__global__ __launch_bounds__(256) void k_edge1(
    const int* __restrict__ ei, const float* __restrict__ pos,
    const unsigned short* __restrict__ y, const float* __restrict__ W1,
    unsigned short* __restrict__ t1, unsigned int* __restrict__ touched,
    long long* __restrict__ stats, int E) {
  const int tid = threadIdx.x, lane = tid & 63, wv = tid >> 6;
  const float wp0 = W1[61 * 64 + lane];
  const float wp1 = W1[62 * 64 + lane];
  const float wp2 = W1[63 * 64 + lane];
  float ssum = 0.f, ssq = 0.f;
  const int wid = blockIdx.x * 4 + wv, nw = gridDim.x * 4;
  for (int e = wid; e < E; e += nw) {
    const int src = ei[e], dst = ei[E + e];
    float pv = 0.f;
    if (lane < 3) pv = pos[src * 3 + lane] - pos[dst * 3 + lane];
    const float p0 = __shfl(pv, 0), p1 = __shfl(pv, 1), p2 = __shfl(pv, 2);
    float t = bf2f(y[(size_t)src * 64 + lane]);
    t = fmaf(p0, wp0, t);
    t = fmaf(p1, wp1, t);
    t = fmaf(p2, wp2, t);
    t = fmaxf(t, 0.f);
    t1[(size_t)e * 64 + lane] = f2bf(t);
    if (lane == 0) touched[dst] = 1u;
    ssum += t;
    ssq = fmaf(t, t, ssq);
  }
  __shared__ float red[256];
  stat_reduce(ssum, red, stats + 0);
  stat_reduce(ssq, red, stats + 64);
}

// ---- BN coef: a = g*rsqrt(var+eps), c = be - mean*a ----
__global__ void k_coef(const long long* __restrict__ sum,
                       const long long* __restrict__ sq,
                       const float* __restrict__ g, const float* __restrict__ be,
                       float* __restrict__ a_out, float* __restrict__ c_out,
                       double inv) {
  int c = threadIdx.x;
  double m = (double)sum[c] * inv;
  double v = (double)sq[c] * inv - m * m;
  float rs = rsqrtf((float)v + EPS);
  float a = g[c] * rs;
  a_out[c] = a;
  c_out[c] = fmaf(-(float)m, a, be[c]);
}

// ---- fold BN1 affine into W2: W2'[k][c] = a1[k]*W2[k][c]; b2'[c] = b2[c]+sum_k c1[k]W2[k][c]
__global__ void k_coefW2(const float* __restrict__ W2, const float* __restrict__ b2,
                         const float* __restrict__ coef, unsigned short* __restrict__ W2p,
                         float* __restrict__ b2p) {
  const int c = threadIdx.x;
  float acc = b2[c];
  for (int k = 0; k < 64; ++k) {
    const float w = W2[k * 64 + c];
    acc = fmaf(coef[64 + k], w, acc);
    W2p[k * 64 + c] = f2bf(coef[k] * w);
  }
  b2p[c] = acc;
}

// ---- edge pass 2 (MFMA): t2 = relu(t1 @ W2' + b2'), stats, scatter-max ----
// wave handles 16 edges x 64 cols: A 16x32 frags direct from global, 8 MFMAs.
// frag k-position convention (same bijection for A and B, so self-consistent):
//   elem i of lane -> k = kstep*32 + (lane>>4)*8 + i
// D layout (m89-verified): col = lane&15 (+16*tile), row = (lane>>4)*4 + j
__global__ __launch_bounds__(256) void k_edge2(
    const unsigned short* __restrict__ t1, const int* __restrict__ ei,
    const unsigned short* __restrict__ W2p, const float* __restrict__ b2p,
    long long* __restrict__ stats, unsigned int* __restrict__ agg, int E) {
  const int tid = threadIdx.x, lane = tid & 63, wv = tid >> 6;
  const int l15 = lane & 15, lg = lane >> 4;
  s16x8 bF[4][2];
#pragma unroll
  for (int t = 0; t < 4; ++t) {
    const int col = l15 + 16 * t;
#pragma unroll
    for (int s = 0; s < 2; ++s)
#pragma unroll
      for (int i = 0; i < 8; ++i)
        bF[t][s][i] = (short)W2p[(s * 32 + lg * 8 + i) * 64 + col];
  }
  float bias[4];
#pragma unroll
  for (int t = 0; t < 4; ++t) bias[t] = b2p[l15 + 16 * t];
  float ssum[4] = {0.f, 0.f, 0.f, 0.f}, ssq[4] = {0.f, 0.f, 0.f, 0.f};
  const int wid = blockIdx.x * 4 + wv, nw = gridDim.x * 4;
  const int ntile = E >> 4;
  for (int tile = wid; tile < ntile; tile += nw) {
    const int rbase = tile << 4;
    const unsigned short* arow = t1 + (size_t)(rbase + l15) * 64 + lg * 8;
    const s16x8 aF0 = *(const s16x8*)(arow);
    const s16x8 aF1 = *(const s16x8*)(arow + 32);
    fx4 acc[4];
#pragma unroll
    for (int t = 0; t < 4; ++t) {
      acc[t][0] = bias[t]; acc[t][1] = bias[t];
      acc[t][2] = bias[t]; acc[t][3] = bias[t];
    }
#pragma unroll
    for (int t = 0; t < 4; ++t) {
      acc[t] = __builtin_amdgcn_mfma_f32_16x16x32_bf16(aF0, bF[t][0], acc[t], 0, 0, 0);
      acc[t] = __builtin_amdgcn_mfma_f32_16x16x32_bf16(aF1, bF[t][1], acc[t], 0, 0, 0);
    }
    int dstr[4];
#pragma unroll
    for (int j = 0; j < 4; ++j) dstr[j] = ei[E + rbase + lg * 4 + j];
#pragma unroll
    for (int t = 0; t < 4; ++t) {
      const int col = l15 + 16 * t;
#pragma unroll
      for (int j = 0; j < 4; ++j) {
        const float v = fmaxf(acc[t][j], 0.f);
        ssum[t] += v;
        ssq[t] = fmaf(v, v, ssq[t]);
        if (v > 0.f)
          atomicMax(&agg[(size_t)dstr[j] * 64 + col], __float_as_uint(v));
      }
    }
  }
#pragma unroll
  for (int t = 0; t < 4; ++t) {
    ssum[t] += __shfl_xor(ssum[t], 16); ssum[t] += __shfl_xor(ssum[t], 32);
    ssq[t]  += __shfl_xor(ssq[t], 16);  ssq[t]  += __shfl_xor(ssq[t], 32);
  }
  __shared__ float sred[2][64];
  if (tid < 128) ((float*)sred)[tid] = 0.f;
  __syncthreads();
  if (lg == 0) {
#pragma unroll
    for (int t = 0; t < 4; ++t) {
      atomicAdd(&sred[0][l15 + 16 * t], ssum[t]);
      atomicAdd(&sred[1][l15 + 16 * t], ssq[t]);
    }
  }
  __syncthreads();
  if (tid < 64) {
    atomicAdd((unsigned long long*)&stats[128 + tid],
              (unsigned long long)(long long)((double)sred[0][tid] * SCALE));
    atomicAdd((unsigned long long*)&stats[192 + tid],
              (unsigned long long)(long long)((double)sred[1][tid] * SCALE));
  }
}

// ---- decode max, apply BN2 affine, zero empty nodes, stats over N ----
__global__ __launch_bounds__(256) void k_aggfix(
    unsigned int* __restrict__ agg, const unsigned int* __restrict__ touched,
    const float* __restrict__ coef, long long* __restrict__ stats, int total) {
  const int tid = threadIdx.x;
  const int c = tid & 63;
  const float a2 = coef[128 + c], c2 = coef[192 + c];
  __shared__ float red[256];
  float ssum = 0.f, ssq = 0.f;
  const int step = gridDim.x * 256;
  for (int i = blockIdx.x * 256 + tid; i < total; i += step) {
    const unsigned int u = agg[i];
    const unsigned int tch = touched[i >> 6];
    const float v = tch ? fmaf(a2, __uint_as_float(u), c2) : 0.f;
    ((float*)agg)[i] = v;
    ssum += v;
    ssq = fmaf(v, v, ssq);
  }
  stat_reduce(ssum, red, stats + 384);
  stat_reduce(ssq, red, stats + 448);
}

__global__ __launch_bounds__(256) void k_final(
    const float* __restrict__ aggf, const float* __restrict__ s,
    const float* __restrict__ coef, float* __restrict__ out, int total) {
  int i = blockIdx.x * 256 + threadIdx.x;
  if (i >= total) return;
  int c = i & 63;
  float v = fmaf(coef[384 + c], aggf[i], coef[448 + c]) +
            fmaf(coef[256 + c], s[i], coef[320 + c]);
  out[i] = fmaxf(v, 0.f);
}

extern "C" void kernel_launch(void* const* d_in, const int* in_sizes, int n_in,
                              void* d_out, int out_size, void* d_ws, size_t ws_size,
                              hipStream_t stream) {
  const float* x   = (const float*)d_in[0];
  const float* pos = (const float*)d_in[1];
  const int*   ei  = (const int*)d_in[2];
  const float* W1  = (const float*)d_in[3];
  const float* b1  = (const float*)d_in[4];
  const float* g1  = (const float*)d_in[5];
  const float* be1 = (const float*)d_in[6];
  const float* W2  = (const float*)d_in[7];
  const float* b2  = (const float*)d_in[8];
  const float* g2  = (const float*)d_in[9];
  const float* be2 = (const float*)d_in[10];
  const float* Ws  = (const float*)d_in[11];
  const float* bs  = (const float*)d_in[12];
  const float* gs  = (const float*)d_in[13];
  const float* bes = (const float*)d_in[14];
  const float* gf  = (const float*)d_in[15];
  const float* bef = (const float*)d_in[16];
  const int N = in_sizes[0] / CIN;   // 50000
  const int E = in_sizes[2] / 2;     // 800000

  char* ws = (char*)d_ws;
  long long* stats      = (long long*)ws;                       // 4 KB
  float* coef           = (float*)(ws + 4096);                  // 576 floats
  float* b2p            = coef + 512;
  unsigned short* W2p   = (unsigned short*)(ws + 8192);         // 8 KB
  unsigned int* touched = (unsigned int*)(ws + 16384);          // N*4
  size_t off = 16384 + (size_t)N * 4;                           // 216384
  unsigned int* agg     = (unsigned int*)(ws + off);            // N*256
  float* sbuf           = (float*)(ws + off + (size_t)N * 256);
  unsigned short* ybuf  = (unsigned short*)(ws + off + (size_t)N * 512);
  unsigned short* t1buf = (unsigned short*)(ws + off + (size_t)N * 512 + (size_t)N * 128);

  const double invE = 1.0 / (SCALE * (double)E);
  const double invN = 1.0 / (SCALE * (double)N);
  const int total = N * 64;

  // zero stats + touched + agg (contiguous prefix through end of agg)
  hipMemsetAsync(d_ws, 0, off + (size_t)N * 256, stream);

  hipLaunchKernelGGL(k_y, dim3(1024), dim3(256), 0, stream, x, W1, b1, ybuf, N);
  hipLaunchKernelGGL(k_short, dim3(1024), dim3(256), 0, stream, x, Ws, bs, sbuf, stats, N);
  hipLaunchKernelGGL(k_edge1, dim3(2048), dim3(256), 0, stream,
                     ei, pos, ybuf, W1, t1buf, touched, stats, E);
  hipLaunchKernelGGL(k_coef, dim3(1), dim3(64), 0, stream,
                     stats + 0, stats + 64, g1, be1, coef + 0, coef + 64, invE);
  hipLaunchKernelGGL(k_coefW2, dim3(1), dim3(64), 0, stream, W2, b2, coef, W2p, b2p);
  hipLaunchKernelGGL(k_edge2, dim3(2048), dim3(256), 0, stream,
                     t1buf, ei, W2p, b2p, stats, agg, E);
  hipLaunchKernelGGL(k_coef, dim3(1), dim3(64), 0, stream,
                     stats + 128, stats + 192, g2, be2, coef + 128, coef + 192, invE);
  hipLaunchKernelGGL(k_coef, dim3(1), dim3(64), 0, stream,
                     stats + 256, stats + 320, gs, bes, coef + 256, coef + 320, invN);
  hipLaunchKernelGGL(k_aggfix, dim3(2048), dim3(256), 0, stream,
                     agg, touched, coef, stats, total);
  hipLaunchKernelGGL(k_coef, dim3(1), dim3(64), 0, stream,
                     stats + 384, stats + 448, gf, bef, coef + 384, coef + 448, invN);
  hipLaunchKernelGGL(k_final, dim3((total + 255) / 256), dim3(256), 0, stream,
                     (const float*)agg, sbuf, coef, (float*)d_out, total);
}